// Round 7
// baseline (142.953 us; speedup 1.0000x reference)
//
#include <hip/hip_runtime.h>
#include <hip/hip_bf16.h>
#include <hip/hip_cooperative_groups.h>

namespace cg = cooperative_groups;

// Problem constants
constexpr int kB   = 4;
constexpr int kC   = 64;
constexpr int kH   = 32;
constexpr int kW   = 32;
constexpr int kO   = 128;
constexpr int kG   = 4;
constexpr int kHW  = kH * kW;  // 1024

// Decomposition
constexpr int kNC   = 8;           // channel chunks
constexpr int kCPC  = kC / kNC;    // 8 channels per chunk
constexpr int kOG   = 8;           // outputs per block
constexpr int kNOG  = kO / kOG;    // 16 o-groups
constexpr int kWP   = 12;          // padded weight row (9 -> 12)
constexpr int kTS   = 48;          // tile row stride: 34 + max rot 12, 16B-aligned
constexpr int kTILE = 34 * kTS;    // floats per channel

__device__ __forceinline__ int rot4(int r) { return r & 12; }

// ---- shared phase-1 body (conv partials) ----
__device__ __forceinline__ void conv_phase(
    const float* __restrict__ x,
    const float* __restrict__ means,
    const int*   __restrict__ col_idx,
    __hip_bfloat16* __restrict__ part,
    float* tile, float* wloc, int idx, int t)
{
    const int og    = (idx & 7) | (((idx >> 3) & 1) << 3);
    const int b     = (idx >> 4) & 3;
    const int chunk = idx >> 6;
    const int o_base = og * kOG;
    const int s_base = chunk * (kCPC * 9);

    // A) issue col_idx + means loads early
    const int ol  = t >> 5;
    const int j0  = t & 31;
    const int o_w = o_base + ol;
    int sidx[8];
    #pragma unroll
    for (int k = 0; k < 8; ++k)
        sidx[k] = col_idx[o_w * 256 + j0 + k * 32];
    const float4 mrow = *reinterpret_cast<const float4*>(&means[o_w * kG]);

    // B) issue x loads early (regs), write LDS later
    const float* xb = x + ((size_t)b * kC + chunk * kCPC) * kHW;
    float4 v[2][8];
    int ch_[2], rr_[2];
    #pragma unroll
    for (int p = 0; p < 2; ++p) {
        const int tau = t + p * 256;
        ch_[p] = tau / 34;
        rr_[p] = tau - ch_[p] * 34;
        if (p == 0 || t < kCPC * 34 - 256) {
            const int hr = rr_[p] - 1;
            if (hr >= 0 && hr < kH) {
                const float4* s4 =
                    reinterpret_cast<const float4*>(xb + ch_[p] * kHW + hr * kW);
                #pragma unroll
                for (int q = 0; q < 8; ++q) v[p][q] = s4[q];
            } else {
                #pragma unroll
                for (int q = 0; q < 8; ++q)
                    v[p][q] = make_float4(0.f, 0.f, 0.f, 0.f);
            }
        }
    }

    // C) build weight chunk under the load latency
    for (int i = t; i < kOG * kCPC * kWP; i += 256) wloc[i] = 0.f;
    __syncthreads();
    {
        const float* mr = reinterpret_cast<const float*>(&mrow);
        #pragma unroll
        for (int k = 0; k < 8; ++k) {
            const int s = sidx[k] - s_base;
            if (s >= 0 && s < kCPC * 9) {
                const int ch_l = s / 9;
                const int kk   = s - ch_l * 9;
                atomicAdd(&wloc[(ol * kCPC + ch_l) * kWP + kk], mr[k >> 1]);
            }
        }
    }

    // D) write staged x into rot-swizzled LDS tile
    #pragma unroll
    for (int p = 0; p < 2; ++p) {
        if (p == 0 || t < kCPC * 34 - 256) {
            float* tp = &tile[ch_[p] * kTILE + rr_[p] * kTS + rot4(rr_[p])];
            float prev = 0.f;
            #pragma unroll
            for (int q = 0; q < 8; ++q) {
                *reinterpret_cast<float4*>(&tp[4 * q]) =
                    make_float4(prev, v[p][q].x, v[p][q].y, v[p][q].z);
                prev = v[p][q].w;
            }
            *reinterpret_cast<float2*>(&tp[32]) = make_float2(prev, 0.f);
        }
    }
    __syncthreads();

    // E) compute: 2 outputs x 4x4 pixels per thread
    const int op0  = (t >> 6) * 2;
    const int lane = t & 63;
    const int r0   = (lane >> 3) * 4;
    const int c0   = (lane & 7) * 4;

    float acc[2][4][4] = {};

    for (int ch = 0; ch < kCPC; ++ch) {
        float xv[6][6];
        #pragma unroll
        for (int i = 0; i < 6; ++i) {
            const int row = r0 + i;
            const float* rp = &tile[ch * kTILE + row * kTS + rot4(row) + c0];
            const float4 a  = *reinterpret_cast<const float4*>(rp);
            const float2 bb = *reinterpret_cast<const float2*>(rp + 4);
            xv[i][0] = a.x;  xv[i][1] = a.y;  xv[i][2] = a.z;
            xv[i][3] = a.w;  xv[i][4] = bb.x; xv[i][5] = bb.y;
        }
        float w0[9], w1[9];
        {
            const float* wp = &wloc[(op0 * kCPC + ch) * kWP];
            const float4 wa = *reinterpret_cast<const float4*>(wp);
            const float4 wb = *reinterpret_cast<const float4*>(wp + 4);
            w0[0]=wa.x; w0[1]=wa.y; w0[2]=wa.z; w0[3]=wa.w;
            w0[4]=wb.x; w0[5]=wb.y; w0[6]=wb.z; w0[7]=wb.w; w0[8]=wp[8];
            const float* wq = &wloc[((op0 + 1) * kCPC + ch) * kWP];
            const float4 wc = *reinterpret_cast<const float4*>(wq);
            const float4 wd = *reinterpret_cast<const float4*>(wq + 4);
            w1[0]=wc.x; w1[1]=wc.y; w1[2]=wc.z; w1[3]=wc.w;
            w1[4]=wd.x; w1[5]=wd.y; w1[6]=wd.z; w1[7]=wd.w; w1[8]=wq[8];
        }
        #pragma unroll
        for (int kh = 0; kh < 3; ++kh)
            #pragma unroll
            for (int kw = 0; kw < 3; ++kw) {
                const float a0 = w0[kh * 3 + kw];
                const float a1 = w1[kh * 3 + kw];
                #pragma unroll
                for (int i = 0; i < 4; ++i)
                    #pragma unroll
                    for (int j = 0; j < 4; ++j) {
                        acc[0][i][j] += a0 * xv[i + kh][j + kw];
                        acc[1][i][j] += a1 * xv[i + kh][j + kw];
                    }
            }
    }

    // F) store bf16 partials
    #pragma unroll
    for (int u = 0; u < 2; ++u) {
        const int o = o_base + op0 + u;
        __hip_bfloat16* dst =
            part + (((size_t)chunk * kB + b) * kO + o) * kHW;
        #pragma unroll
        for (int i = 0; i < 4; ++i) {
            __hip_bfloat162 lo, hi;
            lo.x = __float2bfloat16(acc[u][i][0]);
            lo.y = __float2bfloat16(acc[u][i][1]);
            hi.x = __float2bfloat16(acc[u][i][2]);
            hi.y = __float2bfloat16(acc[u][i][3]);
            union { __hip_bfloat162 h2[2]; uint2 u2; } pk;
            pk.h2[0] = lo; pk.h2[1] = hi;
            *reinterpret_cast<uint2*>(&dst[(r0 + i) * kW + c0]) = pk.u2;
        }
    }
}

// ---- shared phase-2 body (reduce + bias) ----
__device__ __forceinline__ void reduce_phase(
    const __hip_bfloat16* __restrict__ part,
    const float* __restrict__ bias,
    float* __restrict__ out, int i4)
{
    const int px4 = i4 & 255;
    const int bo  = i4 >> 8;
    const int o   = bo & (kO - 1);
    const int b   = bo >> 7;

    float s0 = 0.f, s1 = 0.f, s2 = 0.f, s3 = 0.f;
    #pragma unroll
    for (int n = 0; n < kNC; ++n) {
        const __hip_bfloat16* p =
            part + (((size_t)n * kB + b) * kO + o) * kHW + px4 * 4;
        union { uint2 u2; __hip_bfloat162 h2[2]; } pk;
        pk.u2 = *reinterpret_cast<const uint2*>(p);
        s0 += __bfloat162float(pk.h2[0].x);
        s1 += __bfloat162float(pk.h2[0].y);
        s2 += __bfloat162float(pk.h2[1].x);
        s3 += __bfloat162float(pk.h2[1].y);
    }
    const float bo_ = bias[o];
    reinterpret_cast<float4*>(out)[i4] =
        make_float4(s0 + bo_, s1 + bo_, s2 + bo_, s3 + bo_);
}

// ---- fused cooperative kernel: conv -> grid.sync -> reduce ----
__global__ __launch_bounds__(256, 2) void fused_kernel(
    const float* __restrict__ x,
    const float* __restrict__ means,
    const float* __restrict__ bias,
    const int*   __restrict__ col_idx,
    __hip_bfloat16* __restrict__ part,
    float* __restrict__ out)
{
    __shared__ float tile[kCPC * kTILE];        // 52.2 KB
    __shared__ float wloc[kOG * kCPC * kWP];    // 3 KB

    conv_phase(x, means, col_idx, part, tile, wloc, blockIdx.x, threadIdx.x);

    __threadfence();                 // device-scope release (cross-XCD partials)
    cg::this_grid().sync();

    reduce_phase(part, bias, out, blockIdx.x * 256 + threadIdx.x);
}

// ---- split kernels (fallback if cooperative launch unavailable) ----
__global__ __launch_bounds__(256, 2) void conv_part_kernel(
    const float* __restrict__ x,
    const float* __restrict__ means,
    const int*   __restrict__ col_idx,
    __hip_bfloat16* __restrict__ part)
{
    __shared__ float tile[kCPC * kTILE];
    __shared__ float wloc[kOG * kCPC * kWP];
    conv_phase(x, means, col_idx, part, tile, wloc, blockIdx.x, threadIdx.x);
}

__global__ __launch_bounds__(256) void reduce_kernel(
    const __hip_bfloat16* __restrict__ part,
    const float* __restrict__ bias,
    float* __restrict__ out)
{
    reduce_phase(part, bias, out, blockIdx.x * 256 + threadIdx.x);
}

// ---- fallback if ws too small: direct single-pass conv ----
__global__ __launch_bounds__(256) void conv_direct_kernel(
    const float* __restrict__ x,
    const float* __restrict__ means,
    const float* __restrict__ bias,
    const int*   __restrict__ col_idx,
    float*       __restrict__ out)
{
    __shared__ float tile[34 * 34];
    __shared__ float wloc[kC * 9];

    const int o = blockIdx.x & (kO - 1);
    const int b = blockIdx.x >> 7;
    const int t = threadIdx.x;

    for (int i = t; i < kC * 9; i += 256) wloc[i] = 0.f;
    __syncthreads();
    {
        const int s = col_idx[o * 256 + t];
        atomicAdd(&wloc[s], means[o * kG + (t >> 6)]);
    }

    const int c  = t & 31;
    const int r0 = (t >> 5) * 4;
    const float* xb = x + (size_t)b * kC * kHW;
    float acc[4] = {0.f, 0.f, 0.f, 0.f};

    for (int ch = 0; ch < kC; ++ch) {
        __syncthreads();
        for (int i = t; i < 34 * 34; i += 256) {
            const int rr = i / 34, cc = i - rr * 34;
            const int hr = rr - 1, hc = cc - 1;
            float v = 0.f;
            if (hr >= 0 && hr < kH && hc >= 0 && hc < kW)
                v = xb[ch * kHW + hr * kW + hc];
            tile[i] = v;
        }
        __syncthreads();
        float w[9];
        #pragma unroll
        for (int k = 0; k < 9; ++k) w[k] = wloc[ch * 9 + k];
        float xv[6][3];
        #pragma unroll
        for (int i = 0; i < 6; ++i)
            #pragma unroll
            for (int j = 0; j < 3; ++j)
                xv[i][j] = tile[(r0 + i) * 34 + c + j];
        #pragma unroll
        for (int i = 0; i < 4; ++i)
            #pragma unroll
            for (int kh = 0; kh < 3; ++kh)
                #pragma unroll
                for (int kw = 0; kw < 3; ++kw)
                    acc[i] += w[kh * 3 + kw] * xv[i + kh][kw];
    }
    const float bo = bias[o];
    #pragma unroll
    for (int i = 0; i < 4; ++i)
        out[((size_t)b * kO + o) * kHW + (r0 + i) * kW + c] = acc[i] + bo;
}

extern "C" void kernel_launch(void* const* d_in, const int* in_sizes, int n_in,
                              void* d_out, int out_size, void* d_ws, size_t ws_size,
                              hipStream_t stream)
{
    const float* x       = (const float*)d_in[0];
    const float* means   = (const float*)d_in[1];
    const float* bias    = (const float*)d_in[2];
    const int*   col_idx = (const int*)d_in[3];
    float*       out     = (float*)d_out;

    constexpr size_t kPartBytes =
        (size_t)kNC * kB * kO * kHW * sizeof(__hip_bfloat16);   // 8 MB

    if (ws_size >= kPartBytes) {
        __hip_bfloat16* part = (__hip_bfloat16*)d_ws;
        void* args[] = {(void*)&x, (void*)&means, (void*)&bias,
                        (void*)&col_idx, (void*)&part, (void*)&out};
        hipError_t err = hipLaunchCooperativeKernel(
            (const void*)fused_kernel, dim3(kNC * kB * kNOG), dim3(256),
            args, 0, stream);
        if (err != hipSuccess) {
            // fallback: two-kernel path
            conv_part_kernel<<<kNC * kB * kNOG, 256, 0, stream>>>(
                x, means, col_idx, part);
            reduce_kernel<<<kB * kO, 256, 0, stream>>>(part, bias, out);
        }
    } else {
        conv_direct_kernel<<<kB * kO, 256, 0, stream>>>(
            x, means, bias, col_idx, out);
    }
}

// Round 8
// 17.776 us; speedup vs baseline: 8.0417x; 8.0417x over previous
//
#include <hip/hip_runtime.h>

typedef __attribute__((ext_vector_type(8))) short bf16x8;
typedef __attribute__((ext_vector_type(4))) float f32x4;

// Problem constants
constexpr int kB   = 4;
constexpr int kC   = 64;
constexpr int kH   = 32;
constexpr int kW   = 32;
constexpr int kO   = 128;
constexpr int kG   = 4;
constexpr int kHW  = kH * kW;   // 1024
constexpr int kSEG = kC * 9;    // 576

// bf16 round-to-nearest-even (no NaN inputs here)
__device__ __forceinline__ unsigned short f2bf(float f) {
    union { float f; unsigned u; } v; v.f = f;
    const unsigned r = v.u + 0x7FFFu + ((v.u >> 16) & 1u);
    return (unsigned short)(r >> 16);
}

// Kernel 1: build W_bf16[o][k'] with k' = tap*64 + ch (tap = kh*3+kw).
// dest is repeat(arange(O*G), CS) -> entries for output o are e in
// [o*256, o*256+256), group g = (e%256)>>6. One block per o.
__global__ __launch_bounds__(256) void build_w_kernel(
    const float* __restrict__ means,
    const int*   __restrict__ col_idx,
    unsigned short* __restrict__ Wg)
{
    __shared__ float wacc[kSEG];
    const int o = blockIdx.x, t = threadIdx.x;

    for (int i = t; i < kSEG; i += 256) wacc[i] = 0.f;
    __syncthreads();

    const int s = col_idx[o * 256 + t];
    atomicAdd(&wacc[s], means[o * kG + (t >> 6)]);
    __syncthreads();

    for (int i = t; i < kSEG; i += 256) {
        const int tap = i >> 6;     // 0..8
        const int ch  = i & 63;
        Wg[o * kSEG + i] = f2bf(wacc[ch * 9 + tap]);  // orig s = ch*9 + tap
    }
}

// Kernel 2: implicit-GEMM MFMA conv.
// Grid = 8 o-tiles * 64 px-blocks = 512 (blockIdx = ot*64 + pxb, so blocks
// sharing a px-slab land in the same XCD class for x L2 locality).
// Block: (b, row-pair rp) x-slab staged once in LDS as bf16 [4][34][72-pad];
// 4 waves = 2 px-rows x 2 col-halves, each wave: 16 px x 16 o, K=576 in
// 18 slices of 32 (slice s: tap = s>>1, ch-half = s&1).
__global__ __launch_bounds__(256) void conv_mfma_kernel(
    const float* __restrict__ x,
    const unsigned short* __restrict__ Wg,
    const float* __restrict__ bias,
    float* __restrict__ out)
{
    __shared__ unsigned short xs[4 * 34 * 72];   // 19584 B

    const int bi  = blockIdx.x;
    const int ot  = bi >> 6;          // o-tile 0..7
    const int pxb = bi & 63;
    const int b   = pxb >> 4;
    const int rp  = pxb & 15;         // pixel rows 2rp, 2rp+1
    const int t   = threadIdx.x;
    const int w   = t >> 6;           // wave 0..3
    const int ln  = t & 63;
    const int ln15 = ln & 15;
    const int g    = ln >> 4;         // k-group 0..3
    const int wr   = w >> 1;          // wave pixel row 0/1
    const int c0   = (w & 1) * 16;    // wave pixel col base

    // ---- prefetch 18 B fragments from global W (L2-hot) ----
    const unsigned short* wp = Wg + (ot * 16 + ln15) * kSEG + g * 8;
    bf16x8 bfr[18];
    #pragma unroll
    for (int s = 0; s < 18; ++s)
        bfr[s] = *reinterpret_cast<const bf16x8*>(wp + s * 32);

    // ---- stage x slab: rows 2rp-1 .. 2rp+2, cols -1..32, all 64 ch ----
    // thread = (ch-pair cp 0..31, r4 0..3, col-half 0..1)
    {
        const int cp    = t >> 3;
        const int r4    = (t >> 1) & 3;
        const int chalf = t & 1;
        const int ch0   = cp * 2;
        const int hr    = rp * 2 - 1 + r4;
        const bool rowok = (hr >= 0) && (hr < kH);
        const float* x0 = x + (((size_t)b * kC + ch0) * kH + (rowok ? hr : 0)) * kW;
        const float* x1 = x0 + kHW;              // next channel
        const int hcb = chalf * 16;              // covered hc base

        float4 f0[4], f1[4];
        #pragma unroll
        for (int q = 0; q < 4; ++q) {
            f0[q] = rowok ? *reinterpret_cast<const float4*>(x0 + hcb + q * 4)
                          : make_float4(0.f, 0.f, 0.f, 0.f);
            f1[q] = rowok ? *reinterpret_cast<const float4*>(x1 + hcb + q * 4)
                          : make_float4(0.f, 0.f, 0.f, 0.f);
        }

        if (chalf == 0) {
            // c34 = j: j==0 -> hc=-1 (zero); j=1..16 -> hc=0..15
            #pragma unroll
            for (int j = 0; j < 17; ++j) {
                float v0 = 0.f, v1 = 0.f;
                if (j > 0) {
                    const int h = j - 1;
                    v0 = reinterpret_cast<const float*>(&f0[h >> 2])[h & 3];
                    v1 = reinterpret_cast<const float*>(&f1[h >> 2])[h & 3];
                }
                const unsigned pkv =
                    (unsigned)f2bf(v0) | ((unsigned)f2bf(v1) << 16);
                *reinterpret_cast<unsigned*>(
                    &xs[(r4 * 34 + j) * 72 + ch0]) = pkv;
            }
        } else {
            // c34 = 17+j: j=0..15 -> hc=16..31; j==16 -> hc=32 (zero)
            #pragma unroll
            for (int j = 0; j < 17; ++j) {
                float v0 = 0.f, v1 = 0.f;
                if (j < 16) {
                    v0 = reinterpret_cast<const float*>(&f0[j >> 2])[j & 3];
                    v1 = reinterpret_cast<const float*>(&f1[j >> 2])[j & 3];
                }
                const unsigned pkv =
                    (unsigned)f2bf(v0) | ((unsigned)f2bf(v1) << 16);
                *reinterpret_cast<unsigned*>(
                    &xs[(r4 * 34 + 17 + j) * 72 + ch0]) = pkv;
            }
        }
    }
    __syncthreads();

    // ---- 18 MFMAs: A = patches (M=16 px, K=32), B = W (K=32, N=16 o) ----
    // A lane map: m = ln15 (pixel col c0+ln15), k = g*8 + i.
    // slice s: tap = s>>1 (kh=tap/3, kw=tap%3), half = s&1;
    // A element = xs[wr+kh][c0+ln15+kw][half*32 + g*8 + i].
    f32x4 acc = {0.f, 0.f, 0.f, 0.f};
    #pragma unroll
    for (int s = 0; s < 18; ++s) {
        const int tap  = s >> 1;
        const int half = s & 1;
        const int kh   = tap / 3;
        const int kw   = tap % 3;
        const int r4   = wr + kh;
        const int c34  = c0 + ln15 + kw;
        const bf16x8 a = *reinterpret_cast<const bf16x8*>(
            &xs[(r4 * 34 + c34) * 72 + half * 32 + g * 8]);
        acc = __builtin_amdgcn_mfma_f32_16x16x32_bf16(a, bfr[s], acc, 0, 0, 0);
    }

    // ---- epilogue: D row m = g*4+reg -> pixel col c0+g*4+reg (contig 4),
    // D col = ln15 -> o. float4 store + bias.
    const int o     = ot * 16 + ln15;
    const float bo  = bias[o];
    const int pxrow = rp * 2 + wr;
    const float4 res = make_float4(acc[0] + bo, acc[1] + bo,
                                   acc[2] + bo, acc[3] + bo);
    *reinterpret_cast<float4*>(
        &out[((size_t)(b * kO + o)) * kHW + pxrow * kW + c0 + g * 4]) = res;
}

// Fallback (ws too small): direct single-pass VALU conv, block = (b,o).
__global__ __launch_bounds__(256) void conv_direct_kernel(
    const float* __restrict__ x,
    const float* __restrict__ means,
    const float* __restrict__ bias,
    const int*   __restrict__ col_idx,
    float*       __restrict__ out)
{
    __shared__ float tile[34 * 34];
    __shared__ float wloc[kC * 9];

    const int o = blockIdx.x & (kO - 1);
    const int b = blockIdx.x >> 7;
    const int t = threadIdx.x;

    for (int i = t; i < kC * 9; i += 256) wloc[i] = 0.f;
    __syncthreads();
    {
        const int s = col_idx[o * 256 + t];
        atomicAdd(&wloc[s], means[o * kG + (t >> 6)]);
    }

    const int c  = t & 31;
    const int r0 = (t >> 5) * 4;
    const float* xb = x + (size_t)b * kC * kHW;
    float acc[4] = {0.f, 0.f, 0.f, 0.f};

    for (int ch = 0; ch < kC; ++ch) {
        __syncthreads();
        for (int i = t; i < 34 * 34; i += 256) {
            const int rr = i / 34, cc = i - rr * 34;
            const int hr = rr - 1, hc = cc - 1;
            float v = 0.f;
            if (hr >= 0 && hr < kH && hc >= 0 && hc < kW)
                v = xb[ch * kHW + hr * kW + hc];
            tile[i] = v;
        }
        __syncthreads();
        float wv[9];
        #pragma unroll
        for (int k = 0; k < 9; ++k) wv[k] = wloc[ch * 9 + k];
        float xv[6][3];
        #pragma unroll
        for (int i = 0; i < 6; ++i)
            #pragma unroll
            for (int j = 0; j < 3; ++j)
                xv[i][j] = tile[(r0 + i) * 34 + c + j];
        #pragma unroll
        for (int i = 0; i < 4; ++i)
            #pragma unroll
            for (int kh = 0; kh < 3; ++kh)
                #pragma unroll
                for (int kw = 0; kw < 3; ++kw)
                    acc[i] += wv[kh * 3 + kw] * xv[i + kh][kw];
    }
    const float bo = bias[o];
    #pragma unroll
    for (int i = 0; i < 4; ++i)
        out[((size_t)b * kO + o) * kHW + (r0 + i) * kW + c] = acc[i] + bo;
}

extern "C" void kernel_launch(void* const* d_in, const int* in_sizes, int n_in,
                              void* d_out, int out_size, void* d_ws, size_t ws_size,
                              hipStream_t stream)
{
    const float* x       = (const float*)d_in[0];
    const float* means   = (const float*)d_in[1];
    const float* bias    = (const float*)d_in[2];
    const int*   col_idx = (const int*)d_in[3];
    float*       out     = (float*)d_out;

    constexpr size_t kWBytes = (size_t)kO * kSEG * sizeof(unsigned short); // 144 KB

    if (ws_size >= kWBytes) {
        unsigned short* Wg = (unsigned short*)d_ws;
        build_w_kernel<<<kO, 256, 0, stream>>>(means, col_idx, Wg);
        conv_mfma_kernel<<<512, 256, 0, stream>>>(x, Wg, bias, out);
    } else {
        conv_direct_kernel<<<kB * kO, 256, 0, stream>>>(
            x, means, bias, col_idx, out);
    }
}